// Round 11
// baseline (260.271 us; speedup 1.0000x reference)
//
#include <hip/hip_runtime.h>

#define N_NODES 100000
#define D_IN 32
#define H 64
#define EPS 1e-5f
#define RSTR 32     // bucket row: 2 sub-rows of 16 slots (64B each)
#define SCAP 16     // per-sub-bucket capacity; P(Poisson(6.25)>16)~1e-4
#define HALF 50000  // source-range split
#define OV_CAP 32768

typedef float floatx2 __attribute__((ext_vector_type(2)));

__device__ __forceinline__ unsigned short f2bf(float f) {
    union { float f; unsigned int u; } c; c.f = f;
    unsigned int b = c.u + 0x7FFFu + ((c.u >> 16) & 1u);   // RNE
    return (unsigned short)(b >> 16);
}
__device__ __forceinline__ float bf2f(unsigned short s) {
    union { unsigned int u; float f; } c; c.u = ((unsigned int)s) << 16;
    return c.f;
}

// ================= fused: scatter + MLP, interleaved roles =================
__global__ __launch_bounds__(256, 2) void fused_kernel(
    const float* __restrict__ x,
    const float* __restrict__ W1, const float* __restrict__ b1,
    const float* __restrict__ g1, const float* __restrict__ be1,
    const float* __restrict__ W2, const float* __restrict__ b2,
    const float* __restrict__ g2, const float* __restrict__ be2,
    unsigned short* __restrict__ hb, unsigned char* __restrict__ hb8,
    const int* __restrict__ ei, int* __restrict__ cnt2, int* __restrict__ bkt,
    int* __restrict__ ovCnt, int2* __restrict__ ov,
    int E, int SB, int TOT)
{
    const int i = blockIdx.x;
    const int before = (int)((long long)i * SB / TOT);
    const int after  = (int)((long long)(i + 1) * SB / TOT);

    if (after > before) {
        // ---------------- scatter: 8 edges/thread, source-range sub-buckets ----------------
        int t = before * 256 + threadIdx.x;
        int e0 = t * 8;
        if (e0 >= E) return;

        int rows[8], cols[8], pos[8], gg[8];
        if (e0 + 7 < E) {
            int4 r0 = *(const int4*)(ei + e0);
            int4 r1 = *(const int4*)(ei + e0 + 4);
            int4 c0 = *(const int4*)(ei + E + e0);
            int4 c1 = *(const int4*)(ei + E + e0 + 4);
            rows[0]=r0.x; rows[1]=r0.y; rows[2]=r0.z; rows[3]=r0.w;
            rows[4]=r1.x; rows[5]=r1.y; rows[6]=r1.z; rows[7]=r1.w;
            cols[0]=c0.x; cols[1]=c0.y; cols[2]=c0.z; cols[3]=c0.w;
            cols[4]=c1.x; cols[5]=c1.y; cols[6]=c1.z; cols[7]=c1.w;
        } else {
#pragma unroll
            for (int j = 0; j < 8; ++j) {
                int e = e0 + j;
                if (e < E) { rows[j] = ei[e]; cols[j] = ei[E + e]; }
                else rows[j] = -1;
            }
        }
#pragma unroll
        for (int j = 0; j < 8; ++j) {
            if (rows[j] >= 0) {
                gg[j] = (cols[j] >= HALF) ? 1 : 0;
                pos[j] = atomicAdd(&cnt2[rows[j] * 2 + gg[j]], 1);
            }
        }
#pragma unroll
        for (int j = 0; j < 8; ++j) {
            if (rows[j] < 0) continue;
            if (pos[j] < SCAP) {
                __builtin_nontemporal_store(cols[j],
                    &bkt[rows[j] * RSTR + gg[j] * SCAP + pos[j]]);
            } else {
                int s = atomicAdd(ovCnt, 1);
                if (s < OV_CAP) ov[s] = make_int2(rows[j], cols[j]);
            }
        }
        return;
    }

    // ---------------- MLP: thread-per-node ----------------
    int gid = (i - before) * 256 + threadIdx.x;
    int node = gid < N_NODES ? gid : N_NODES - 1;

    float xr[D_IN];
    {
        const float4* xp = (const float4*)(x + (long long)node * D_IN);
#pragma unroll
        for (int i2 = 0; i2 < D_IN / 4; ++i2) {
            float4 v = xp[i2];
            xr[4*i2+0] = v.x; xr[4*i2+1] = v.y; xr[4*i2+2] = v.z; xr[4*i2+3] = v.w;
        }
    }

    float h1[H];
#pragma unroll
    for (int jb = 0; jb < H / 4; ++jb) {
        float4 b = *(const float4*)(b1 + jb * 4);
        h1[4*jb+0] = b.x; h1[4*jb+1] = b.y; h1[4*jb+2] = b.z; h1[4*jb+3] = b.w;
    }
#pragma unroll
    for (int k = 0; k < D_IN; ++k) {
        float xk = xr[k];
#pragma unroll
        for (int jb = 0; jb < H / 4; ++jb) {
            float4 w = *(const float4*)(W1 + k * H + jb * 4);
            h1[4*jb+0] += xk * w.x; h1[4*jb+1] += xk * w.y;
            h1[4*jb+2] += xk * w.z; h1[4*jb+3] += xk * w.w;
        }
    }
    {
        float s0=0,s1=0,s2=0,s3=0, q0=0,q1=0,q2=0,q3=0;
#pragma unroll
        for (int j = 0; j < H; j += 4) {
            s0 += h1[j+0]; s1 += h1[j+1]; s2 += h1[j+2]; s3 += h1[j+3];
            q0 += h1[j+0]*h1[j+0]; q1 += h1[j+1]*h1[j+1];
            q2 += h1[j+2]*h1[j+2]; q3 += h1[j+3]*h1[j+3];
        }
        float mu  = (s0+s1+s2+s3) * (1.0f / H);
        float var = (q0+q1+q2+q3) * (1.0f / H) - mu * mu;
        float rs  = rsqrtf(var + EPS);
#pragma unroll
        for (int jb = 0; jb < H / 4; ++jb) {
            float4 g = *(const float4*)(g1 + jb * 4);
            float4 be = *(const float4*)(be1 + jb * 4);
            h1[4*jb+0] = fmaxf((h1[4*jb+0]-mu)*rs*g.x + be.x, 0.0f);
            h1[4*jb+1] = fmaxf((h1[4*jb+1]-mu)*rs*g.y + be.y, 0.0f);
            h1[4*jb+2] = fmaxf((h1[4*jb+2]-mu)*rs*g.z + be.z, 0.0f);
            h1[4*jb+3] = fmaxf((h1[4*jb+3]-mu)*rs*g.w + be.w, 0.0f);
        }
    }

    float h2[H];
#pragma unroll
    for (int jb = 0; jb < H / 4; ++jb) {
        float4 b = *(const float4*)(b2 + jb * 4);
        h2[4*jb+0] = b.x; h2[4*jb+1] = b.y; h2[4*jb+2] = b.z; h2[4*jb+3] = b.w;
    }
#pragma unroll
    for (int k = 0; k < H; ++k) {
        float hk = h1[k];
#pragma unroll
        for (int jb = 0; jb < H / 4; ++jb) {
            float4 w = *(const float4*)(W2 + k * H + jb * 4);
            h2[4*jb+0] += hk * w.x; h2[4*jb+1] += hk * w.y;
            h2[4*jb+2] += hk * w.z; h2[4*jb+3] += hk * w.w;
        }
    }
    {
        float s0=0,s1=0,s2=0,s3=0, q0=0,q1=0,q2=0,q3=0;
#pragma unroll
        for (int j = 0; j < H; j += 4) {
            s0 += h2[j+0]; s1 += h2[j+1]; s2 += h2[j+2]; s3 += h2[j+3];
            q0 += h2[j+0]*h2[j+0]; q1 += h2[j+1]*h2[j+1];
            q2 += h2[j+2]*h2[j+2]; q3 += h2[j+3]*h2[j+3];
        }
        float mu  = (s0+s1+s2+s3) * (1.0f / H);
        float var = (q0+q1+q2+q3) * (1.0f / H) - mu * mu;
        float rs  = rsqrtf(var + EPS);

        unsigned short* hp = hb + (long long)node * H;
        unsigned int w8[H / 4];
#pragma unroll
        for (int jb = 0; jb < H / 4; ++jb) {
            float4 g = *(const float4*)(g2 + jb * 4);
            float4 be = *(const float4*)(be2 + jb * 4);
            float4 v;
            v.x = fmaxf((h2[4*jb+0]-mu)*rs*g.x + be.x, 0.0f);
            v.y = fmaxf((h2[4*jb+1]-mu)*rs*g.y + be.y, 0.0f);
            v.z = fmaxf((h2[4*jb+2]-mu)*rs*g.z + be.z, 0.0f);
            v.w = fmaxf((h2[4*jb+3]-mu)*rs*g.w + be.w, 0.0f);
            ushort4 u;
            u.x = f2bf(v.x); u.y = f2bf(v.y); u.z = f2bf(v.z); u.w = f2bf(v.w);
            *(ushort4*)(hp + 4*jb) = u;
            int lo = __builtin_amdgcn_cvt_pk_fp8_f32(v.x, v.y, 0, false);
            w8[jb] = (unsigned int)__builtin_amdgcn_cvt_pk_fp8_f32(v.z, v.w, lo, true);
        }
        unsigned int* hp8 = (unsigned int*)(hb8 + (long long)node * H);
#pragma unroll
        for (int q = 0; q < H / 16; ++q)
            *(uint4*)(hp8 + q * 4) = make_uint4(w8[4*q+0], w8[4*q+1], w8[4*q+2], w8[4*q+3]);
    }
}

// ================= aggregation pass g: gathers confined to 3.2MB hb8 range =================
// Per pass, every gather lands in hb8[range g] (3.2MB < 4MB per-XCD L2) ->
// random transactions served by XCD-local L2 instead of the shared LLC path
// (measured ~15G lines/s cap). Pass 0: out = self + acc. Pass 1: out += acc (+ov).
__global__ __launch_bounds__(256) void aggr_kernel(
    const int* __restrict__ cnt2, const int* __restrict__ bkt,
    const unsigned short* __restrict__ hb, const unsigned char* __restrict__ hb8,
    float* __restrict__ out,
    const int* __restrict__ ovCnt, const int2* __restrict__ ov, int g)
{
    const int t    = threadIdx.x & 63;
    const int sub  = t >> 4;                       // node-within-wave
    const int c    = t & 15;                       // channel quad
    const int wave = blockIdx.x * 4 + (threadIdx.x >> 6);
    const int node = wave * 4 + sub;               // grid exact: 6250*16 = 100000

    int m = cnt2[node * 2 + g];
    if (m > SCAP) m = SCAP;
    const int base = node * RSTR + g * SCAP;
    const unsigned int* h8 = (const unsigned int*)hb8;  // row stride 16 uints

    float a0 = 0.f, a1 = 0.f, a2 = 0.f, a3 = 0.f;
    int cc[SCAP];
#pragma unroll
    for (int i = 0; i < SCAP; ++i)                 // one 64B sub-row, broadcast loads
        cc[i] = bkt[base + i];
    unsigned int vv[SCAP];
#pragma unroll
    for (int i = 0; i < SCAP; ++i)                 // independent 4B gathers (64B rows)
        if (i < m) vv[i] = h8[(cc[i] << 4) + c];
#pragma unroll
    for (int i = 0; i < SCAP; ++i) {
        if (i < m) {
            floatx2 p0 = __builtin_amdgcn_cvt_pk_f32_fp8(vv[i], false);
            floatx2 p1 = __builtin_amdgcn_cvt_pk_f32_fp8(vv[i], true);
            a0 += p0.x; a1 += p0.y; a2 += p1.x; a3 += p1.y;
        }
    }

    float* op = out + ((long long)node << 6) + (c << 2);
    if (g == 0) {
        // self term (bf16) + first write
        uint2 sv = *(const uint2*)(hb + ((long long)node << 6) + (c << 2));
        a0 += bf2f((unsigned short)(sv.x & 0xFFFFu));
        a1 += bf2f((unsigned short)(sv.x >> 16));
        a2 += bf2f((unsigned short)(sv.y & 0xFFFFu));
        a3 += bf2f((unsigned short)(sv.y >> 16));
        *(float4*)op = make_float4(a0, a1, a2, a3);
    } else {
        // exact overflow drain (expected ~20 entries total)
        int nov = *ovCnt; if (nov > OV_CAP) nov = OV_CAP;
        for (int i = 0; i < nov; ++i) {
            int2 rc = ov[i];
            if (rc.x == node) {
                uint2 vb = *(const uint2*)(hb + ((long long)rc.y << 6) + (c << 2));
                a0 += bf2f((unsigned short)(vb.x & 0xFFFFu));
                a1 += bf2f((unsigned short)(vb.x >> 16));
                a2 += bf2f((unsigned short)(vb.y & 0xFFFFu));
                a3 += bf2f((unsigned short)(vb.y >> 16));
            }
        }
        float4 prev = *(float4*)op;                // sole writer, no atomics
        *(float4*)op = make_float4(prev.x + a0, prev.y + a1, prev.z + a2, prev.w + a3);
    }
}

extern "C" void kernel_launch(void* const* d_in, const int* in_sizes, int n_in,
                              void* d_out, int out_size, void* d_ws, size_t ws_size,
                              hipStream_t stream)
{
    const float* x   = (const float*)d_in[0];
    const int*   ei  = (const int*)d_in[1];
    const float* W1  = (const float*)d_in[2];
    const float* b1  = (const float*)d_in[3];
    const float* g1  = (const float*)d_in[4];
    const float* be1 = (const float*)d_in[5];
    const float* W2  = (const float*)d_in[6];
    const float* b2  = (const float*)d_in[7];
    const float* g2  = (const float*)d_in[8];
    const float* be2 = (const float*)d_in[9];

    float* out = (float*)d_out;

    // workspace layout (~33.3 MB)
    char* ws = (char*)d_ws;
    unsigned short* hb    = (unsigned short*)ws;              // 12,800,000 B
    unsigned char*  hb8   = (unsigned char*)(ws + 12800000);  //  6,400,000 B
    int*            cnt2  = (int*)(ws + 19200000);            //    800,000 B
    int*            ovCnt = (int*)(ws + 20000000);            //         64 B
    int2*           ov    = (int2*)(ws + 20000064);           //    262,144 B
    int*            bkt   = (int*)(ws + 20262208);            // 12,800,000 B (nt-written, never zeroed)

    const int E = in_sizes[1] / 2;

    hipMemsetAsync(cnt2, 0, 800064, stream);                  // cnt2 + ovCnt

    const int SB = ((E + 7) / 8 + 255) / 256;                 // 611 scatter blocks
    const int MB = (N_NODES + 255) / 256;                     // 391 mlp blocks
    fused_kernel<<<SB + MB, 256, 0, stream>>>(
        x, W1, b1, g1, be1, W2, b2, g2, be2, hb, hb8,
        ei, cnt2, bkt, ovCnt, ov, E, SB, SB + MB);

    aggr_kernel<<<N_NODES / 16, 256, 0, stream>>>(cnt2, bkt, hb, hb8, out, ovCnt, ov, 0);
    aggr_kernel<<<N_NODES / 16, 256, 0, stream>>>(cnt2, bkt, hb, hb8, out, ovCnt, ov, 1);
}